// Round 17
// baseline (182.435 us; speedup 1.0000x reference)
//
#include <hip/hip_runtime.h>
#include <hip/hip_bf16.h>
#include <stdint.h>

typedef int v4i __attribute__((ext_vector_type(4)));

#define TOK 8192   // B*S
#define DIN 4096   // K (bytes per row, int8)
#define DOUT 4096  // N

#define NT 32      // K-tiles: 4096 / 128 bytes

// ---------------- Kernel 1: per-token dynamic quantization ----------------
__global__ __launch_bounds__(256) void quant_rows(const float* __restrict__ x,
                                                  int8_t* __restrict__ xq,
                                                  float* __restrict__ ascale) {
    const int row = blockIdx.x;
    const int t = threadIdx.x;
    const float* __restrict__ xr = x + (size_t)row * DIN;
    float4 v[4];
    float amax = 0.0f;
#pragma unroll
    for (int i = 0; i < 4; ++i) {
        v[i] = reinterpret_cast<const float4*>(xr)[t + 256 * i];
        amax = fmaxf(amax, fmaxf(fmaxf(fabsf(v[i].x), fabsf(v[i].y)),
                                 fmaxf(fabsf(v[i].z), fabsf(v[i].w))));
    }
#pragma unroll
    for (int off = 1; off < 64; off <<= 1)
        amax = fmaxf(amax, __shfl_xor(amax, off, 64));
    __shared__ float wmax[4];
    if ((t & 63) == 0) wmax[t >> 6] = amax;
    __syncthreads();
    amax = fmaxf(fmaxf(wmax[0], wmax[1]), fmaxf(wmax[2], wmax[3]));
    const float scale = fmaxf(amax, 1e-8f) / 127.0f;  // exact ref semantics
    if (t == 0) ascale[row] = scale;
    uint32_t* __restrict__ qr = reinterpret_cast<uint32_t*>(xq + (size_t)row * DIN);
#pragma unroll
    for (int i = 0; i < 4; ++i) {
        // IEEE div + rintf (half-even) == jnp.round(x / act_scale)
        int q0 = (int)fminf(fmaxf(rintf(v[i].x / scale), -128.0f), 127.0f);
        int q1 = (int)fminf(fmaxf(rintf(v[i].y / scale), -128.0f), 127.0f);
        int q2 = (int)fminf(fmaxf(rintf(v[i].z / scale), -128.0f), 127.0f);
        int q3 = (int)fminf(fmaxf(rintf(v[i].w / scale), -128.0f), 127.0f);
        qr[t + 256 * i] = (uint32_t)((q0 & 0xFF) | ((q1 & 0xFF) << 8) |
                                     ((q2 & 0xFF) << 16) | ((q3 & 0xFF) << 24));
    }
}

// ---------------- Kernel 2: weight repack int32 -> int8 ----------------
__global__ __launch_bounds__(256) void pack_w(const int* __restrict__ wq,
                                              uint32_t* __restrict__ w8) {
    const size_t i = (size_t)blockIdx.x * 256 + threadIdx.x;
    int4 a = reinterpret_cast<const int4*>(wq)[i];
    w8[i] = (uint32_t)((a.x & 0xFF) | ((a.y & 0xFF) << 8) |
                       ((a.z & 0xFF) << 16) | ((a.w & 0xFF) << 24));
}

// ---------------- Kernel 3: int8 GEMM, 256x256 tile -----------------------
// FINAL (declared): best verified configuration (R9/R15). 2-phase-per-K-tile
// schedule (4 barriers/iteration) with within-phase counted lgkmcnt and
// asm-opaque counted vmcnt (the +49% lever: keeps prefetches in flight
// across barriers; compiler cannot insert drains). PA: stage next tile's B;
// pre-read aT/bL split k0/k1 (lgkmcnt(6) starts MFMA after 6 reads); window
// reads bR,aB drain at counted points under Q1/Q2; lgkmcnt(0) at PA end
// drains aB BEFORE the barrier (cross-wave WAR rule: drain -> barrier ->
// stage). PB: stage A-halves; 32 wait-free MFMAs; VM(4) certifies the next
// tile (FIFO queue [v.A(4), v.B(4), u'.A(4)] -> 4). XOR-swizzled LDS
// (quarter-varying slot law: conflict-free, SQ_LDS_BANK_CONFLICT = 0),
// applied inverse at the global source + forward at ds_read (linear
// global_load_lds dest). Exact int32 accumulate -> bit-exact vs reference;
// fused dequant epilogue: y = acc * ascale[m] * wscale[n] + bias[n].
__global__ __launch_bounds__(512, 2) void gemm_i8(const int8_t* __restrict__ A,
                                                  const int8_t* __restrict__ B,
                                                  const float* __restrict__ ascale,
                                                  const float* __restrict__ wscale,
                                                  const float* __restrict__ bias,
                                                  float* __restrict__ C) {
    __shared__ __attribute__((aligned(16))) uint8_t lds[131072];  // A:[0,64K) B:[64K,128K)
    const int tid = threadIdx.x;
    const int bn = blockIdx.x, bm = blockIdx.y;

    // ---- staging precompute (inverse-swizzled global source, linear dest)
    const int srow = tid >> 3;  // row within 128-row half
    const int sp = tid & 7;     // 16B slot within 128B row
    const size_t soff0 = (size_t)srow * DIN + (size_t)(((sp ^ (srow & 7)) * 16));
    const size_t soff1 = soff0 + (size_t)64 * DIN;  // (srow+64)&7 == srow&7
    const uint32_t dst0 = (uint32_t)tid * 16u;
    const uint32_t dst1 = dst0 + 8192u;
    const int8_t* gA = A + (size_t)bm * 256 * DIN;
    const int8_t* gB = B + (size_t)bn * 256 * DIN;

#define STAGE_HALF(gmat, rbase, bufv, h, ktc)                                            \
    do {                                                                                 \
        const int8_t* _s = (gmat) + ((size_t)(h)*128 * DIN) + ((size_t)(ktc)*128);       \
        const uint32_t _d = (rbase) + (uint32_t)(bufv)*32768u + (uint32_t)(h)*16384u;    \
        __builtin_amdgcn_global_load_lds(                                                \
            (const __attribute__((address_space(1))) void*)(_s + soff0),                 \
            (__attribute__((address_space(3))) void*)(&lds[_d + dst0]), 16, 0, 0);       \
        __builtin_amdgcn_global_load_lds(                                                \
            (const __attribute__((address_space(1))) void*)(_s + soff1),                 \
            (__attribute__((address_space(3))) void*)(&lds[_d + dst1]), 16, 0, 0);       \
    } while (0)

    // ---- wave / lane geometry
    const int wid = tid >> 6, l = tid & 63;
    const int wm = (wid >> 2) * 128;  // 2 M-waves
    const int wn = (wid & 3) * 64;    // 4 N-waves
    const int lr = l & 15, lg = l >> 4;
    // swizzled k-slot offsets for the two K=64 sub-MFMAs of a 128B K-step
    const uint32_t koff0 = (uint32_t)(((lg) ^ (l & 7)) * 16);
    const uint32_t koff1 = (uint32_t)(((4 + lg) ^ (l & 7)) * 16);
    // per-lane ds_read base registers (koff folded in; buf1 = +32768)
    const uint32_t aRd = (uint32_t)((wm >> 7) * 16384 + lr * 128);
    const uint32_t bRd = 65536u + (uint32_t)((wn >> 7) * 16384 + ((wn & 64) + lr) * 128);
    const uint32_t a0_0 = aRd + koff0, a1_0 = aRd + koff1;
    const uint32_t a0_1 = a0_0 + 32768u, a1_1 = a1_0 + 32768u;
    const uint32_t b0_0 = bRd + koff0, b1_0 = bRd + koff1;
    const uint32_t b0_1 = b0_0 + 32768u, b1_1 = b1_0 + 32768u;

    v4i acc[8][4];
#pragma unroll
    for (int i = 0; i < 8; ++i)
#pragma unroll
        for (int j = 0; j < 4; ++j) acc[i][j] = (v4i){0, 0, 0, 0};

    v4i aT[4][2], aB[4][2], bL[2][2], bR[2][2];

#define DSR(d, b, o) asm volatile("ds_read_b128 %0, %1 offset:" o : "=v"(d) : "v"(b))

    // k0/k1-split read groups (FIFO counts depend on these exact sizes)
#define RD_AT0(A0)                                             \
    do {                                                       \
        DSR(aT[0][0], A0, "0");    DSR(aT[1][0], A0, "2048");  \
        DSR(aT[2][0], A0, "4096"); DSR(aT[3][0], A0, "6144");  \
    } while (0)
#define RD_AT1(A1)                                             \
    do {                                                       \
        DSR(aT[0][1], A1, "0");    DSR(aT[1][1], A1, "2048");  \
        DSR(aT[2][1], A1, "4096"); DSR(aT[3][1], A1, "6144");  \
    } while (0)
#define RD_AB0(A0)                                                \
    do {                                                          \
        DSR(aB[0][0], A0, "8192");  DSR(aB[1][0], A0, "10240");   \
        DSR(aB[2][0], A0, "12288"); DSR(aB[3][0], A0, "14336");   \
    } while (0)
#define RD_AB1(A1)                                                \
    do {                                                          \
        DSR(aB[0][1], A1, "8192");  DSR(aB[1][1], A1, "10240");   \
        DSR(aB[2][1], A1, "12288"); DSR(aB[3][1], A1, "14336");   \
    } while (0)
#define RD_BL0(B0)                                             \
    do { DSR(bL[0][0], B0, "0"); DSR(bL[1][0], B0, "2048"); } while (0)
#define RD_BL1(B1)                                             \
    do { DSR(bL[0][1], B1, "0"); DSR(bL[1][1], B1, "2048"); } while (0)
#define RD_BR0(B0)                                             \
    do { DSR(bR[0][0], B0, "4096"); DSR(bR[1][0], B0, "6144"); } while (0)
#define RD_BR1(B1)                                             \
    do { DSR(bR[0][1], B1, "4096"); DSR(bR[1][1], B1, "6144"); } while (0)

#define BAR() asm volatile("s_barrier" ::: "memory")
#define LGKM(n)                                                     \
    do {                                                            \
        asm volatile("s_waitcnt lgkmcnt(" #n ")" ::: "memory");     \
        __builtin_amdgcn_sched_barrier(0);                          \
    } while (0)
#define PRIO1() __builtin_amdgcn_s_setprio(1)
#define PRIO0()                                \
    do {                                       \
        __builtin_amdgcn_sched_barrier(0);     \
        __builtin_amdgcn_s_setprio(0);         \
    } while (0)
#define VM(n) asm volatile("s_waitcnt vmcnt(" #n ")" ::: "memory")

    // 8 MFMAs at fixed kk (4 mi x 2 ni); kk=1 pass depends on kk=0 at
    // distance 8 (same acc), never back-to-back.
#define MFMA_KK(AF, BF, MB, NB, KK)                                                      \
    do {                                                                                 \
        _Pragma("unroll") for (int mi = 0; mi < 4; ++mi)                                 \
        _Pragma("unroll") for (int ni = 0; ni < 2; ++ni) {                               \
            acc[(MB) + mi][(NB) + ni] = __builtin_amdgcn_mfma_i32_16x16x64_i8(           \
                AF[mi][(KK)], BF[ni][(KK)], acc[(MB) + mi][(NB) + ni], 0, 0, 0);         \
        }                                                                                \
    } while (0)

    // PA: Q1+Q2 on tile in bufX; stage next tile's B into bufY.
    // lgkm FIFO: pre k0(6) | pre k1(6) | bR(4) | aB(8)
#define PHASE_A(A0, A1, B0, B1, sbuf, ktc)          \
    do {                                            \
        BAR();                                      \
        STAGE_HALF(gB, 65536u, sbuf, 0, ktc);       \
        STAGE_HALF(gB, 65536u, sbuf, 1, ktc);       \
        RD_AT0(A0); RD_BL0(B0);   /* k0 set: 6 */   \
        RD_AT1(A1); RD_BL1(B1);   /* k1 set: 6 */   \
        LGKM(6);                  /* k0 landed */   \
        PRIO1();                                    \
        RD_BR0(B0); RD_BR1(B1);   /* +4 -> 10 */    \
        RD_AB0(A0); RD_AB1(A1);   /* +8 -> 18 */    \
        MFMA_KK(aT, bL, 0, 0, 0); /* Q1 k0 */       \
        LGKM(12);                 /* k1 landed */   \
        MFMA_KK(aT, bL, 0, 0, 1); /* Q1 k1 */       \
        LGKM(8);                  /* bR landed */   \
        MFMA_KK(aT, bR, 0, 2, 0); /* Q2 k0 */       \
        MFMA_KK(aT, bR, 0, 2, 1); /* Q2 k1 */       \
        LGKM(0);                  /* aB landed (drain BEFORE barrier) */ \
        PRIO0();                                    \
    } while (0)

    // PB: Q3+Q4 (wait-free); stage next-next tile's A into sbuf; VM(4) cert.
#define PHASE_B(sbuf, ktc)                          \
    do {                                            \
        BAR();                                      \
        STAGE_HALF(gA, 0u, sbuf, 0, ktc);           \
        STAGE_HALF(gA, 0u, sbuf, 1, ktc);           \
        PRIO1();                                    \
        MFMA_KK(aB, bL, 4, 0, 0);                   \
        MFMA_KK(aB, bL, 4, 0, 1);                   \
        MFMA_KK(aB, bR, 4, 2, 0);                   \
        MFMA_KK(aB, bR, 4, 2, 1);                   \
        PRIO0();                                    \
        VM(4);                                      \
    } while (0)

    // ---- prologue: stage kt0 (all 4 halves) + kt1 (A halves); cert kt0.
    // Loop invariant entering PHASE_A: outstanding = next tile's A = 4 loads.
    STAGE_HALF(gA, 0u, 0, 0, 0);
    STAGE_HALF(gA, 0u, 0, 1, 0);
    STAGE_HALF(gB, 65536u, 0, 0, 0);
    STAGE_HALF(gB, 65536u, 0, 1, 0);
    STAGE_HALF(gA, 0u, 1, 0, 1);
    STAGE_HALF(gA, 0u, 1, 1, 1);
    VM(4);  // kt0's 8 loads drained; kt1.A (4) in flight

    // ---- main loop: u=2t (buf0), v=2t+1 (buf1); 4 phases, 4 barriers/iter
    for (int t = 0; t < NT / 2; ++t) {
        const int cv = 2 * t + 1;
        const int cu2 = (2 * t + 2 < NT) ? 2 * t + 2 : NT - 1;  // clamp: dead stage
        const int cv2 = (2 * t + 3 < NT) ? 2 * t + 3 : NT - 1;

        // PA(u): compute u.Q1/Q2 from buf0 | stage v.B -> buf1
        PHASE_A(a0_0, a1_0, b0_0, b1_0, 1, cv);
        // PB(u): compute u.Q3/Q4 | stage u'.A -> buf0 | VM(4): v certified
        PHASE_B(0, cu2);
        // PA(v): compute v.Q1/Q2 from buf1 | stage u'.B -> buf0
        PHASE_A(a0_1, a1_1, b0_1, b1_1, 0, cu2);
        // PB(v): compute v.Q3/Q4 | stage v'.A -> buf1 | VM(4): u' certified
        PHASE_B(1, cv2);
    }

    // drain clamped prefetches
    VM(0);

    // ---- epilogue: C/D layout col=lane&15, row=(lane>>4)*4+reg
    const int col0 = bn * 256 + wn + lr;
    float wsv[4], bbv[4];
#pragma unroll
    for (int ni = 0; ni < 4; ++ni) {
        wsv[ni] = wscale[col0 + ni * 16];
        bbv[ni] = bias[col0 + ni * 16];
    }
    const int rbase = bm * 256 + wm + lg * 4;
#pragma unroll
    for (int mi = 0; mi < 8; ++mi) {
#pragma unroll
        for (int r = 0; r < 4; ++r) {
            const int row = rbase + mi * 16 + r;
            const float as = ascale[row];
            float* __restrict__ crow = C + (size_t)row * DOUT;
#pragma unroll
            for (int ni = 0; ni < 4; ++ni) {
                crow[col0 + ni * 16] = (float)acc[mi][ni][r] * as * wsv[ni] + bbv[ni];
            }
        }
    }
#undef STAGE_HALF
#undef DSR
#undef RD_AT0
#undef RD_AT1
#undef RD_AB0
#undef RD_AB1
#undef RD_BL0
#undef RD_BL1
#undef RD_BR0
#undef RD_BR1
#undef BAR
#undef LGKM
#undef PRIO1
#undef PRIO0
#undef VM
#undef MFMA_KK
#undef PHASE_A
#undef PHASE_B
}

extern "C" void kernel_launch(void* const* d_in, const int* in_sizes, int n_in,
                              void* d_out, int out_size, void* d_ws, size_t ws_size,
                              hipStream_t stream) {
    const float* x = (const float*)d_in[0];
    const int* wq = (const int*)d_in[1];
    const float* wscale = (const float*)d_in[2];
    const float* bias = (const float*)d_in[3];
    float* out = (float*)d_out;

    // workspace: xq[TOK*DIN] i8 | w8[DOUT*DIN] i8 | ascale[TOK] f32
    int8_t* xq = (int8_t*)d_ws;
    int8_t* w8 = xq + (size_t)TOK * DIN;
    float* ascale = (float*)(w8 + (size_t)DOUT * DIN);

    quant_rows<<<TOK, 256, 0, stream>>>(x, xq, ascale);
    pack_w<<<(int)(((size_t)DOUT * DIN / 4) / 256), 256, 0, stream>>>(wq, (uint32_t*)w8);
    gemm_i8<<<dim3(DOUT / 256, TOK / 256), 512, 0, stream>>>(xq, w8, ascale, wscale, bias, out);
}

// Round 18
// 179.855 us; speedup vs baseline: 1.0143x; 1.0143x over previous
//
#include <hip/hip_runtime.h>
#include <hip/hip_bf16.h>
#include <stdint.h>

typedef int v4i __attribute__((ext_vector_type(4)));

#define TOK 8192   // B*S
#define DIN 4096   // K (bytes per row, int8)
#define DOUT 4096  // N

#define NT 32      // K-tiles: 4096 / 128 bytes

// ---------------- Kernel 1: fused prep (quant + weight repack) ------------
// Blocks [0, TOK): per-token dynamic quantization of x (one row each).
// Blocks [TOK, TOK+16384): int32 -> int8 weight repack (4096B each).
// The two halves are independent memory-bound grids; fusing them removes
// one dispatch gap and overlaps their tails. Branch is block-uniform.
__global__ __launch_bounds__(256) void prep(const float* __restrict__ x,
                                            const int* __restrict__ wq,
                                            int8_t* __restrict__ xq,
                                            uint32_t* __restrict__ w8,
                                            float* __restrict__ ascale) {
    const int t = threadIdx.x;
    if (blockIdx.x < TOK) {
        const int row = blockIdx.x;
        const float* __restrict__ xr = x + (size_t)row * DIN;
        float4 v[4];
        float amax = 0.0f;
#pragma unroll
        for (int i = 0; i < 4; ++i) {
            v[i] = reinterpret_cast<const float4*>(xr)[t + 256 * i];
            amax = fmaxf(amax, fmaxf(fmaxf(fabsf(v[i].x), fabsf(v[i].y)),
                                     fmaxf(fabsf(v[i].z), fabsf(v[i].w))));
        }
#pragma unroll
        for (int off = 1; off < 64; off <<= 1)
            amax = fmaxf(amax, __shfl_xor(amax, off, 64));
        __shared__ float wmax[4];
        if ((t & 63) == 0) wmax[t >> 6] = amax;
        __syncthreads();
        amax = fmaxf(fmaxf(wmax[0], wmax[1]), fmaxf(wmax[2], wmax[3]));
        const float scale = fmaxf(amax, 1e-8f) / 127.0f;  // exact ref semantics
        if (t == 0) ascale[row] = scale;
        uint32_t* __restrict__ qr = reinterpret_cast<uint32_t*>(xq + (size_t)row * DIN);
#pragma unroll
        for (int i = 0; i < 4; ++i) {
            // IEEE div + rintf (half-even) == jnp.round(x / act_scale)
            int q0 = (int)fminf(fmaxf(rintf(v[i].x / scale), -128.0f), 127.0f);
            int q1 = (int)fminf(fmaxf(rintf(v[i].y / scale), -128.0f), 127.0f);
            int q2 = (int)fminf(fmaxf(rintf(v[i].z / scale), -128.0f), 127.0f);
            int q3 = (int)fminf(fmaxf(rintf(v[i].w / scale), -128.0f), 127.0f);
            qr[t + 256 * i] = (uint32_t)((q0 & 0xFF) | ((q1 & 0xFF) << 8) |
                                         ((q2 & 0xFF) << 16) | ((q3 & 0xFF) << 24));
        }
    } else {
        const size_t i = (size_t)(blockIdx.x - TOK) * 256 + t;
        int4 a = reinterpret_cast<const int4*>(wq)[i];
        w8[i] = (uint32_t)((a.x & 0xFF) | ((a.y & 0xFF) << 8) |
                           ((a.z & 0xFF) << 16) | ((a.w & 0xFF) << 24));
    }
}

// ---------------- Kernel 2: int8 GEMM, 256x256 tile -----------------------
// FINAL: best verified configuration (R9/R15/R17, byte-identical).
// 2-phase-per-K-tile schedule (4 barriers/iteration) with within-phase
// counted lgkmcnt and asm-opaque counted vmcnt (the +49% lever: keeps
// prefetches in flight across barriers; compiler cannot insert drains).
// PA: stage next tile's B; pre-read aT/bL split k0/k1 (lgkmcnt(6) starts
// MFMA after 6 reads); window reads bR,aB drain at counted points under
// Q1/Q2; lgkmcnt(0) at PA end drains aB BEFORE the barrier (cross-wave WAR
// rule: drain -> barrier -> stage). PB: stage A-halves; 32 wait-free MFMAs;
// VM(4) certifies the next tile (FIFO queue [v.A(4), v.B(4), u'.A(4)] -> 4).
// XOR-swizzled LDS (quarter-varying slot law: SQ_LDS_BANK_CONFLICT = 0).
// Exact int32 accumulate -> bit-exact vs reference; fused dequant epilogue.
__global__ __launch_bounds__(512, 2) void gemm_i8(const int8_t* __restrict__ A,
                                                  const int8_t* __restrict__ B,
                                                  const float* __restrict__ ascale,
                                                  const float* __restrict__ wscale,
                                                  const float* __restrict__ bias,
                                                  float* __restrict__ C) {
    __shared__ __attribute__((aligned(16))) uint8_t lds[131072];  // A:[0,64K) B:[64K,128K)
    const int tid = threadIdx.x;
    const int bn = blockIdx.x, bm = blockIdx.y;

    // ---- staging precompute (inverse-swizzled global source, linear dest)
    const int srow = tid >> 3;  // row within 128-row half
    const int sp = tid & 7;     // 16B slot within 128B row
    const size_t soff0 = (size_t)srow * DIN + (size_t)(((sp ^ (srow & 7)) * 16));
    const size_t soff1 = soff0 + (size_t)64 * DIN;  // (srow+64)&7 == srow&7
    const uint32_t dst0 = (uint32_t)tid * 16u;
    const uint32_t dst1 = dst0 + 8192u;
    const int8_t* gA = A + (size_t)bm * 256 * DIN;
    const int8_t* gB = B + (size_t)bn * 256 * DIN;

#define STAGE_HALF(gmat, rbase, bufv, h, ktc)                                            \
    do {                                                                                 \
        const int8_t* _s = (gmat) + ((size_t)(h)*128 * DIN) + ((size_t)(ktc)*128);       \
        const uint32_t _d = (rbase) + (uint32_t)(bufv)*32768u + (uint32_t)(h)*16384u;    \
        __builtin_amdgcn_global_load_lds(                                                \
            (const __attribute__((address_space(1))) void*)(_s + soff0),                 \
            (__attribute__((address_space(3))) void*)(&lds[_d + dst0]), 16, 0, 0);       \
        __builtin_amdgcn_global_load_lds(                                                \
            (const __attribute__((address_space(1))) void*)(_s + soff1),                 \
            (__attribute__((address_space(3))) void*)(&lds[_d + dst1]), 16, 0, 0);       \
    } while (0)

    // ---- wave / lane geometry
    const int wid = tid >> 6, l = tid & 63;
    const int wm = (wid >> 2) * 128;  // 2 M-waves
    const int wn = (wid & 3) * 64;    // 4 N-waves
    const int lr = l & 15, lg = l >> 4;
    // swizzled k-slot offsets for the two K=64 sub-MFMAs of a 128B K-step
    const uint32_t koff0 = (uint32_t)(((lg) ^ (l & 7)) * 16);
    const uint32_t koff1 = (uint32_t)(((4 + lg) ^ (l & 7)) * 16);
    // per-lane ds_read base registers (koff folded in; buf1 = +32768)
    const uint32_t aRd = (uint32_t)((wm >> 7) * 16384 + lr * 128);
    const uint32_t bRd = 65536u + (uint32_t)((wn >> 7) * 16384 + ((wn & 64) + lr) * 128);
    const uint32_t a0_0 = aRd + koff0, a1_0 = aRd + koff1;
    const uint32_t a0_1 = a0_0 + 32768u, a1_1 = a1_0 + 32768u;
    const uint32_t b0_0 = bRd + koff0, b1_0 = bRd + koff1;
    const uint32_t b0_1 = b0_0 + 32768u, b1_1 = b1_0 + 32768u;

    v4i acc[8][4];
#pragma unroll
    for (int i = 0; i < 8; ++i)
#pragma unroll
        for (int j = 0; j < 4; ++j) acc[i][j] = (v4i){0, 0, 0, 0};

    v4i aT[4][2], aB[4][2], bL[2][2], bR[2][2];

#define DSR(d, b, o) asm volatile("ds_read_b128 %0, %1 offset:" o : "=v"(d) : "v"(b))

    // k0/k1-split read groups (FIFO counts depend on these exact sizes)
#define RD_AT0(A0)                                             \
    do {                                                       \
        DSR(aT[0][0], A0, "0");    DSR(aT[1][0], A0, "2048");  \
        DSR(aT[2][0], A0, "4096"); DSR(aT[3][0], A0, "6144");  \
    } while (0)
#define RD_AT1(A1)                                             \
    do {                                                       \
        DSR(aT[0][1], A1, "0");    DSR(aT[1][1], A1, "2048");  \
        DSR(aT[2][1], A1, "4096"); DSR(aT[3][1], A1, "6144");  \
    } while (0)
#define RD_AB0(A0)                                                \
    do {                                                          \
        DSR(aB[0][0], A0, "8192");  DSR(aB[1][0], A0, "10240");   \
        DSR(aB[2][0], A0, "12288"); DSR(aB[3][0], A0, "14336");   \
    } while (0)
#define RD_AB1(A1)                                                \
    do {                                                          \
        DSR(aB[0][1], A1, "8192");  DSR(aB[1][1], A1, "10240");   \
        DSR(aB[2][1], A1, "12288"); DSR(aB[3][1], A1, "14336");   \
    } while (0)
#define RD_BL0(B0)                                             \
    do { DSR(bL[0][0], B0, "0"); DSR(bL[1][0], B0, "2048"); } while (0)
#define RD_BL1(B1)                                             \
    do { DSR(bL[0][1], B1, "0"); DSR(bL[1][1], B1, "2048"); } while (0)
#define RD_BR0(B0)                                             \
    do { DSR(bR[0][0], B0, "4096"); DSR(bR[1][0], B0, "6144"); } while (0)
#define RD_BR1(B1)                                             \
    do { DSR(bR[0][1], B1, "4096"); DSR(bR[1][1], B1, "6144"); } while (0)

#define BAR() asm volatile("s_barrier" ::: "memory")
#define LGKM(n)                                                     \
    do {                                                            \
        asm volatile("s_waitcnt lgkmcnt(" #n ")" ::: "memory");     \
        __builtin_amdgcn_sched_barrier(0);                          \
    } while (0)
#define PRIO1() __builtin_amdgcn_s_setprio(1)
#define PRIO0()                                \
    do {                                       \
        __builtin_amdgcn_sched_barrier(0);     \
        __builtin_amdgcn_s_setprio(0);         \
    } while (0)
#define VM(n) asm volatile("s_waitcnt vmcnt(" #n ")" ::: "memory")

    // 8 MFMAs at fixed kk (4 mi x 2 ni); kk=1 pass depends on kk=0 at
    // distance 8 (same acc), never back-to-back.
#define MFMA_KK(AF, BF, MB, NB, KK)                                                      \
    do {                                                                                 \
        _Pragma("unroll") for (int mi = 0; mi < 4; ++mi)                                 \
        _Pragma("unroll") for (int ni = 0; ni < 2; ++ni) {                               \
            acc[(MB) + mi][(NB) + ni] = __builtin_amdgcn_mfma_i32_16x16x64_i8(           \
                AF[mi][(KK)], BF[ni][(KK)], acc[(MB) + mi][(NB) + ni], 0, 0, 0);         \
        }                                                                                \
    } while (0)

    // PA: Q1+Q2 on tile in bufX; stage next tile's B into bufY.
    // lgkm FIFO: pre k0(6) | pre k1(6) | bR(4) | aB(8)
#define PHASE_A(A0, A1, B0, B1, sbuf, ktc)          \
    do {                                            \
        BAR();                                      \
        STAGE_HALF(gB, 65536u, sbuf, 0, ktc);       \
        STAGE_HALF(gB, 65536u, sbuf, 1, ktc);       \
        RD_AT0(A0); RD_BL0(B0);   /* k0 set: 6 */   \
        RD_AT1(A1); RD_BL1(B1);   /* k1 set: 6 */   \
        LGKM(6);                  /* k0 landed */   \
        PRIO1();                                    \
        RD_BR0(B0); RD_BR1(B1);   /* +4 -> 10 */    \
        RD_AB0(A0); RD_AB1(A1);   /* +8 -> 18 */    \
        MFMA_KK(aT, bL, 0, 0, 0); /* Q1 k0 */       \
        LGKM(12);                 /* k1 landed */   \
        MFMA_KK(aT, bL, 0, 0, 1); /* Q1 k1 */       \
        LGKM(8);                  /* bR landed */   \
        MFMA_KK(aT, bR, 0, 2, 0); /* Q2 k0 */       \
        MFMA_KK(aT, bR, 0, 2, 1); /* Q2 k1 */       \
        LGKM(0);                  /* aB landed (drain BEFORE barrier) */ \
        PRIO0();                                    \
    } while (0)

    // PB: Q3+Q4 (wait-free); stage next-next tile's A into sbuf; VM(4) cert.
#define PHASE_B(sbuf, ktc)                          \
    do {                                            \
        BAR();                                      \
        STAGE_HALF(gA, 0u, sbuf, 0, ktc);           \
        STAGE_HALF(gA, 0u, sbuf, 1, ktc);           \
        PRIO1();                                    \
        MFMA_KK(aB, bL, 4, 0, 0);                   \
        MFMA_KK(aB, bL, 4, 0, 1);                   \
        MFMA_KK(aB, bR, 4, 2, 0);                   \
        MFMA_KK(aB, bR, 4, 2, 1);                   \
        PRIO0();                                    \
        VM(4);                                      \
    } while (0)

    // ---- prologue: stage kt0 (all 4 halves) + kt1 (A halves); cert kt0.
    // Loop invariant entering PHASE_A: outstanding = next tile's A = 4 loads.
    STAGE_HALF(gA, 0u, 0, 0, 0);
    STAGE_HALF(gA, 0u, 0, 1, 0);
    STAGE_HALF(gB, 65536u, 0, 0, 0);
    STAGE_HALF(gB, 65536u, 0, 1, 0);
    STAGE_HALF(gA, 0u, 1, 0, 1);
    STAGE_HALF(gA, 0u, 1, 1, 1);
    VM(4);  // kt0's 8 loads drained; kt1.A (4) in flight

    // ---- main loop: u=2t (buf0), v=2t+1 (buf1); 4 phases, 4 barriers/iter
    for (int t = 0; t < NT / 2; ++t) {
        const int cv = 2 * t + 1;
        const int cu2 = (2 * t + 2 < NT) ? 2 * t + 2 : NT - 1;  // clamp: dead stage
        const int cv2 = (2 * t + 3 < NT) ? 2 * t + 3 : NT - 1;

        // PA(u): compute u.Q1/Q2 from buf0 | stage v.B -> buf1
        PHASE_A(a0_0, a1_0, b0_0, b1_0, 1, cv);
        // PB(u): compute u.Q3/Q4 | stage u'.A -> buf0 | VM(4): v certified
        PHASE_B(0, cu2);
        // PA(v): compute v.Q1/Q2 from buf1 | stage u'.B -> buf0
        PHASE_A(a0_1, a1_1, b0_1, b1_1, 0, cu2);
        // PB(v): compute v.Q3/Q4 | stage v'.A -> buf1 | VM(4): u' certified
        PHASE_B(1, cv2);
    }

    // drain clamped prefetches
    VM(0);

    // ---- epilogue: C/D layout col=lane&15, row=(lane>>4)*4+reg
    const int col0 = bn * 256 + wn + lr;
    float wsv[4], bbv[4];
#pragma unroll
    for (int ni = 0; ni < 4; ++ni) {
        wsv[ni] = wscale[col0 + ni * 16];
        bbv[ni] = bias[col0 + ni * 16];
    }
    const int rbase = bm * 256 + wm + lg * 4;
#pragma unroll
    for (int mi = 0; mi < 8; ++mi) {
#pragma unroll
        for (int r = 0; r < 4; ++r) {
            const int row = rbase + mi * 16 + r;
            const float as = ascale[row];
            float* __restrict__ crow = C + (size_t)row * DOUT;
#pragma unroll
            for (int ni = 0; ni < 4; ++ni) {
                crow[col0 + ni * 16] = (float)acc[mi][ni][r] * as * wsv[ni] + bbv[ni];
            }
        }
    }
#undef STAGE_HALF
#undef DSR
#undef RD_AT0
#undef RD_AT1
#undef RD_AB0
#undef RD_AB1
#undef RD_BL0
#undef RD_BL1
#undef RD_BR0
#undef RD_BR1
#undef BAR
#undef LGKM
#undef PRIO1
#undef PRIO0
#undef VM
#undef MFMA_KK
#undef PHASE_A
#undef PHASE_B
}

extern "C" void kernel_launch(void* const* d_in, const int* in_sizes, int n_in,
                              void* d_out, int out_size, void* d_ws, size_t ws_size,
                              hipStream_t stream) {
    const float* x = (const float*)d_in[0];
    const int* wq = (const int*)d_in[1];
    const float* wscale = (const float*)d_in[2];
    const float* bias = (const float*)d_in[3];
    float* out = (float*)d_out;

    // workspace: xq[TOK*DIN] i8 | w8[DOUT*DIN] i8 | ascale[TOK] f32
    int8_t* xq = (int8_t*)d_ws;
    int8_t* w8 = xq + (size_t)TOK * DIN;
    float* ascale = (float*)(w8 + (size_t)DOUT * DIN);

    const int packBlocks = (int)(((size_t)DOUT * DIN / 4) / 256);  // 16384
    prep<<<TOK + packBlocks, 256, 0, stream>>>(x, wq, xq, (uint32_t*)w8, ascale);
    gemm_i8<<<dim3(DOUT / 256, TOK / 256), 512, 0, stream>>>(xq, w8, ascale, wscale, bias, out);
}